// Round 19
// baseline (89.002 us; speedup 1.0000x reference)
//
#include <hip/hip_runtime.h>

// SlidingWindowPyramidAttention — MFMA convs + register bilinear gather.
// B=4, C=256, H=W=64, ws=8 -> 256 windows x 64 positions; NH=8, HD=32, NL=3, NP=4.
//
// MFMA convention (HW-verified r3/r4): mfma(X,Y,acc) -> D[m][n];
//   X-frag: lane holds X[m = mtile+(lane&15)][k = ks*32+(lane>>4)*8 + 0..7]
//   Y-frag: lane holds Y[k same slice][n = ntile+(lane&15)]
//   D-frag: col(lane&15) = n, row = mtile + (lane>>4)*4 + r
//
// r19 = r17's k_all (r18's ILP staging was neutral: compiler re-serialized,
// VGPR stayed 68) + k_gout split by s-half: grid 512 = (window, shalf),
// single 33.8KB slab staged per level -> 2 blocks/CU; gather runs on t<128
// with sq = shalf*32 + (t>>2) (gather body text unchanged); op GEMM covers
// nt in {0,1} (its 32 s columns). Halves k_gout's serial work per block.

#define CC   256
#define CH   128
#define NPT  4
#define NLV  3
#define SS   64
#define NWIN 256

#define QT_PAD  264   // qT row pitch (bf16)
#define HT_PAD  136   // hT row pitch (bf16)
#define AW_PAD  100   // awS row pitch (f32)
#define VST_PAD 264   // vsT row pitch (bf16)

// bf16 weight pool offsets (elements) in d_ws after PXY+A
#define W_SO1 0
#define W_AW1 32768
#define W_SO2 65536
#define W_AW2 90112
#define W_VP  102400
#define W_OP  167936
#define W_TOT 233472

// d_ws byte offsets (high-water 44.5 MB, proven envelope)
#define WS_PXY  0
#define WS_A    12582912
#define WS_WB   18874368
#define WS_VBG  19341312   // bf16 [256*3][64][256] = 25165824 B

typedef short bf16x8 __attribute__((ext_vector_type(8)));
typedef short bf16x4 __attribute__((ext_vector_type(4)));
typedef float f32x4  __attribute__((ext_vector_type(4)));

__device__ __forceinline__ int rfl(int x) { return __builtin_amdgcn_readfirstlane(x); }

__device__ __forceinline__ unsigned short f2bf(float f) {
    unsigned u = __builtin_bit_cast(unsigned, f);
    u += 0x7FFFu + ((u >> 16) & 1u);           // RNE
    return (unsigned short)(u >> 16);
}
__device__ __forceinline__ float bf2f(short s) {
    unsigned u = ((unsigned)(unsigned short)s) << 16;
    return __builtin_bit_cast(float, u);
}
__device__ __forceinline__ bf16x8 pack8(const float* v) {
    bf16x8 r;
    #pragma unroll
    for (int i = 0; i < 8; i++) r[i] = (short)f2bf(v[i]);
    return r;
}
__device__ __forceinline__ int xcd_swz(int bid) {   // 256 blocks, bijective
    return ((bid & 7) << 5) | (bid >> 3);
}

// ---------------------------------------------------------------------------
// K0: fp32 -> bf16 weight conversion (idempotent).
// ---------------------------------------------------------------------------
struct WPack {
    const float *s0, *s1, *s2, *s3, *s4, *s5;
    unsigned short* d;
};
__global__ __launch_bounds__(256) void k_cvt(WPack p) {
    int i = (blockIdx.x * 256 + threadIdx.x) * 8;
    if (i >= W_TOT) return;
    const float* src; int off;
    if      (i < W_AW1) { src = p.s0; off = W_SO1; }
    else if (i < W_SO2) { src = p.s1; off = W_AW1; }
    else if (i < W_AW2) { src = p.s2; off = W_SO2; }
    else if (i < W_VP)  { src = p.s3; off = W_AW2; }
    else if (i < W_OP)  { src = p.s4; off = W_VP;  }
    else                { src = p.s5; off = W_OP;  }
    const float* s = src + (i - off);
    float4 a = *(const float4*)s;
    float4 b = *(const float4*)(s + 4);
    float tmp[8] = {a.x, a.y, a.z, a.w, b.x, b.y, b.z, b.w};
    *(bf16x8*)(p.d + i) = pack8(tmp);
}

// ---------------------------------------------------------------------------
// K1: merged heads + vp-projection, 51200 B LDS -> 3 blocks/CU.
//   bid <  512: heads (kind = bid>>8), aliased-awS layout verbatim (r17).
//   bid >= 512: vp per (window, level), single-buffer form verbatim (r17),
//               then coalesced bit-exact copy buf -> VBG global.
// ---------------------------------------------------------------------------
__global__ __launch_bounds__(256, 2) void k_all(
    const float* __restrict__ query, const float* __restrict__ values,
    const unsigned short* __restrict__ wso1, const float* __restrict__ so_b1,
    const float* __restrict__ so_g,  const float* __restrict__ so_be,
    const unsigned short* __restrict__ wso2, const float* __restrict__ so_b2,
    const unsigned short* __restrict__ waw1, const float* __restrict__ aw_b1,
    const float* __restrict__ aw_g,  const float* __restrict__ aw_be,
    const unsigned short* __restrict__ waw2, const float* __restrict__ aw_b2,
    const unsigned short* __restrict__ wvp, const float* __restrict__ vp_b,
    const float* __restrict__ lemb,
    float2* __restrict__ PXY, float* __restrict__ A,
    unsigned short* __restrict__ VBG)
{
    extern __shared__ char smem[];
    const int bid = blockIdx.x;
    const int t  = threadIdx.x;
    const int lane = t & 63;
    const int g  = rfl(t >> 6);
    const int kc = (lane >> 4) * 8;
    const int srow = (lane >> 3) * 64 + (lane & 7);

    if (bid < 512) {
        // ======= heads path (aliased-awS layout, r17 verbatim) ==============
        unsigned short* qT = (unsigned short*)smem;                 // [64][264]
        unsigned short* hT = (unsigned short*)(smem + 33792);       // [64][136]
        float* awS = (float*)smem;                                  // aliases qT

        const int kind = bid >> 8;
        const int bw = xcd_swz(bid & 255);
        const int b  = bw >> 6;
        const int wy = (bw >> 3) & 7;
        const int wx = bw & 7;

        const unsigned short* w1 = kind ? waw1 : wso1;
        const float* B1 = kind ? aw_b1 : so_b1;
        const float* G  = kind ? aw_g  : so_g;
        const float* Be = kind ? aw_be : so_be;

        // ---- stage qT[s][c] bf16
        {
            const float* qb = query + (size_t)b * CC * 4096 + wy * 8 * 64 + wx * 8;
            for (int it = 0; it < 8; it++) {
                int cg = g * 8 + it;
                float tmp[8];
                #pragma unroll
                for (int j = 0; j < 8; j++)
                    tmp[j] = qb[(size_t)(cg * 8 + j) * 4096 + srow];
                *(bf16x8*)(qT + lane * QT_PAD + cg * 8) = pack8(tmp);
            }
        }
        __syncthreads();

        // ---- conv1 GEMM (256->128), wave g -> rows [g*32,+32)
        f32x4 acc1[2][4];
        #pragma unroll
        for (int mt = 0; mt < 2; mt++)
            #pragma unroll
            for (int nt = 0; nt < 4; nt++) acc1[mt][nt] = (f32x4){0.f, 0.f, 0.f, 0.f};
        for (int ks = 0; ks < 8; ks++) {
            const int c = ks * 32 + kc;
            bf16x8 bq[4];
            #pragma unroll
            for (int nt = 0; nt < 4; nt++)
                bq[nt] = *(const bf16x8*)(qT + (nt * 16 + (lane & 15)) * QT_PAD + c);
            #pragma unroll
            for (int mt = 0; mt < 2; mt++) {
                const int o = g * 32 + mt * 16 + (lane & 15);
                bf16x8 af = *(const bf16x8*)(w1 + (size_t)o * CC + c);
                #pragma unroll
                for (int nt = 0; nt < 4; nt++)
                    acc1[mt][nt] = __builtin_amdgcn_mfma_f32_16x16x32_bf16(af, bq[nt], acc1[mt][nt], 0, 0, 0);
            }
        }

        // ---- GN(+bias,ReLU): wave g's mtile mt == GN group 2g+mt
        #pragma unroll
        for (int mt = 0; mt < 2; mt++) {
            const int c2b = g * 32 + mt * 16 + ((lane >> 4) << 2);
            float4 bv = *(const float4*)(B1 + c2b);
            float s = 0.f, q = 0.f;
            #pragma unroll
            for (int nt = 0; nt < 4; nt++)
                #pragma unroll
                for (int r = 0; r < 4; r++) {
                    float v = acc1[mt][nt][r] + ((const float*)&bv)[r];
                    acc1[mt][nt][r] = v;
                    s += v; q += v * v;
                }
            #pragma unroll
            for (int off = 1; off < 64; off <<= 1) {
                s += __shfl_xor(s, off, 64);
                q += __shfl_xor(q, off, 64);
            }
            const float mu = s * (1.f / 1024.f);
            const float rs = rsqrtf(q * (1.f / 1024.f) - mu * mu + 1e-5f);
            float4 Gv  = *(const float4*)(G + c2b);
            float4 Bev = *(const float4*)(Be + c2b);
            #pragma unroll
            for (int nt = 0; nt < 4; nt++) {
                int ss = nt * 16 + (lane & 15);
                bf16x4 pk;
                #pragma unroll
                for (int r = 0; r < 4; r++) {
                    float val = (acc1[mt][nt][r] - mu) * rs * ((const float*)&Gv)[r]
                                + ((const float*)&Bev)[r];
                    pk[r] = (short)f2bf(fmaxf(val, 0.f));
                }
                *(bf16x4*)(hT + ss * HT_PAD + c2b) = pk;
            }
        }
        __syncthreads();   // qT reads done; awS may now overwrite its space

        if (!kind) {
            // ---- conv2-so (128->192) -> PXY
            f32x4 acc2[3][4];
            #pragma unroll
            for (int mt = 0; mt < 3; mt++)
                #pragma unroll
                for (int nt = 0; nt < 4; nt++) acc2[mt][nt] = (f32x4){0.f, 0.f, 0.f, 0.f};
            for (int ks = 0; ks < 4; ks++) {
                const int c = ks * 32 + kc;
                bf16x8 bh[4];
                #pragma unroll
                for (int nt = 0; nt < 4; nt++)
                    bh[nt] = *(const bf16x8*)(hT + (nt * 16 + (lane & 15)) * HT_PAD + c);
                #pragma unroll
                for (int mt = 0; mt < 3; mt++) {
                    const int o = g * 48 + mt * 16 + (lane & 15);
                    bf16x8 af = *(const bf16x8*)(wso2 + (size_t)o * CH + c);
                    #pragma unroll
                    for (int nt = 0; nt < 4; nt++)
                        acc2[mt][nt] = __builtin_amdgcn_mfma_f32_16x16x32_bf16(af, bh[nt], acc2[mt][nt], 0, 0, 0);
                }
            }
            #pragma unroll
            for (int mt = 0; mt < 3; mt++) {
                const int o_base = g * 48 + mt * 16 + ((lane >> 4) << 2);
                float4 sb = *(const float4*)(so_b2 + o_base);
                #pragma unroll
                for (int nt = 0; nt < 4; nt++) {
                    const int s = nt * 16 + (lane & 15);
                    const float refx = (s & 7) * (1.f / 7.f);
                    const float refy = (s >> 3) * (1.f / 7.f);
                    auto mkp = [](float refc, float oc) {
                        float lc = fminf(fmaxf(refc + oc * 0.125f, 0.f), 1.f);
                        return fminf(fmaxf(lc * 8.f - 0.5f, 0.f), 7.f);
                    };
                    float4 out4;
                    out4.x = mkp(refx, acc2[mt][nt][0] + sb.x);
                    out4.y = mkp(refy, acc2[mt][nt][1] + sb.y);
                    out4.z = mkp(refx, acc2[mt][nt][2] + sb.z);
                    out4.w = mkp(refy, acc2[mt][nt][3] + sb.w);
                    *(float4*)(PXY + (size_t)bw * 6144 + s * 96 + (o_base >> 1)) = out4;
                }
            }
        } else {
            // ---- conv2-aw (128->96) -> awS logits
            for (int mm = 0; mm < 2; mm++) {
                const int mtile = g + mm * 4;
                if (mtile >= 6) break;   // wave-uniform
                f32x4 acc3[4];
                #pragma unroll
                for (int nt = 0; nt < 4; nt++) acc3[nt] = (f32x4){0.f, 0.f, 0.f, 0.f};
                for (int ks = 0; ks < 4; ks++) {
                    const int c = ks * 32 + kc;
                    const int o = mtile * 16 + (lane & 15);
                    bf16x8 af = *(const bf16x8*)(waw2 + (size_t)o * CH + c);
                    #pragma unroll
                    for (int nt = 0; nt < 4; nt++) {
                        bf16x8 bh = *(const bf16x8*)(hT + (nt * 16 + (lane & 15)) * HT_PAD + c);
                        acc3[nt] = __builtin_amdgcn_mfma_f32_16x16x32_bf16(af, bh, acc3[nt], 0, 0, 0);
                    }
                }
                const int o_base = mtile * 16 + ((lane >> 4) << 2);
                float4 ab = *(const float4*)(aw_b2 + o_base);
                #pragma unroll
                for (int nt = 0; nt < 4; nt++) {
                    const int s = nt * 16 + (lane & 15);
                    float4 o4;
                    o4.x = acc3[nt][0] + ab.x;
                    o4.y = acc3[nt][1] + ab.y;
                    o4.z = acc3[nt][2] + ab.z;
                    o4.w = acc3[nt][3] + ab.w;
                    *(float4*)(awS + s * AW_PAD + o_base) = o4;
                }
            }
            __syncthreads();
            // softmax over 12 per (s,h)
            for (int task = t; task < 512; task += 256) {
                const int s = task >> 3, h = task & 7;
                const float* row = awS + s * AW_PAD + h * 12;
                float4 r0 = *(const float4*)row;
                float4 r1 = *(const float4*)(row + 4);
                float4 r2 = *(const float4*)(row + 8);
                float v[12] = {r0.x, r0.y, r0.z, r0.w, r1.x, r1.y, r1.z, r1.w,
                               r2.x, r2.y, r2.z, r2.w};
                float m = v[0];
                #pragma unroll
                for (int j = 1; j < 12; j++) m = fmaxf(m, v[j]);
                float sum = 0.f;
                #pragma unroll
                for (int j = 0; j < 12; j++) { v[j] = __expf(v[j] - m); sum += v[j]; }
                float rinv = 1.f / sum;
                float* dst = A + (size_t)bw * 6144 + s * 96 + h * 12;
                float4 w0 = {v[0] * rinv, v[1] * rinv, v[2] * rinv, v[3] * rinv};
                float4 w1v = {v[4] * rinv, v[5] * rinv, v[6] * rinv, v[7] * rinv};
                float4 w2 = {v[8] * rinv, v[9] * rinv, v[10] * rinv, v[11] * rinv};
                *(float4*)dst = w0;
                *(float4*)(dst + 4) = w1v;
                *(float4*)(dst + 8) = w2;
            }
        }
    } else {
        // ======= vp path (single-buffer form, r17 verbatim) =================
        unsigned short* buf = (unsigned short*)smem;   // [64][264]: stage, then Vb

        const int id = bid - 512;
        const int l  = id >> 8;
        const int bw = xcd_swz(id & 255);
        const int b  = bw >> 6;
        const int wy = (bw >> 3) & 7;
        const int wx = bw & 7;

        // ---- stage buf[s][c] bf16 (+ level embed)
        {
            const float* vb = values + ((size_t)(b * NLV + l) * CC) * 4096 + wy * 8 * 64 + wx * 8;
            const float* le = lemb + l * CC;
            for (int it = 0; it < 8; it++) {
                int cg = g * 8 + it;
                float tmp[8];
                #pragma unroll
                for (int j = 0; j < 8; j++) {
                    int c = cg * 8 + j;
                    tmp[j] = vb[(size_t)c * 4096 + srow] + le[c];
                }
                *(bf16x8*)(buf + lane * VST_PAD + cg * 8) = pack8(tmp);
            }
        }
        __syncthreads();

        // ---- vp GEMM (m=o, n=s): wave g -> o in [g*64,+64)
        {
            f32x4 acc[4][4];
            #pragma unroll
            for (int mt = 0; mt < 4; mt++)
                #pragma unroll
                for (int nt = 0; nt < 4; nt++) acc[mt][nt] = (f32x4){0.f, 0.f, 0.f, 0.f};
            for (int ks = 0; ks < 8; ks++) {
                const int c = ks * 32 + kc;
                bf16x8 bf[4];
                #pragma unroll
                for (int nt = 0; nt < 4; nt++)
                    bf[nt] = *(const bf16x8*)(buf + (nt * 16 + (lane & 15)) * VST_PAD + c);
                #pragma unroll
                for (int mt = 0; mt < 4; mt++) {
                    const int o = g * 64 + mt * 16 + (lane & 15);
                    bf16x8 af = *(const bf16x8*)(wvp + (size_t)o * CC + c);
                    #pragma unroll
                    for (int nt = 0; nt < 4; nt++)
                        acc[mt][nt] = __builtin_amdgcn_mfma_f32_16x16x32_bf16(
                            af, bf[nt], acc[mt][nt], 0, 0, 0);
                }
            }
            __syncthreads();   // all stage reads done; buf may be overwritten

            // ---- write Vb[s][o] bf16 into the same buffer
            #pragma unroll
            for (int mt = 0; mt < 4; mt++) {
                const int o0 = g * 64 + mt * 16 + ((lane >> 4) << 2);
                float4 bv = *(const float4*)(vp_b + o0);
                #pragma unroll
                for (int nt = 0; nt < 4; nt++) {
                    const int s = nt * 16 + (lane & 15);
                    bf16x4 pk;
                    #pragma unroll
                    for (int r = 0; r < 4; r++)
                        pk[r] = (short)f2bf(acc[mt][nt][r] + ((const float*)&bv)[r]);
                    *(bf16x4*)(buf + s * VST_PAD + o0) = pk;
                }
            }
        }
        __syncthreads();

        // ---- bit-exact coalesced copy buf LDS -> VBG global (128 B/thread)
        {
            unsigned short* dst = VBG + ((size_t)(bw * 3 + l)) * 64 * 256;
            for (int j = t; j < 2048; j += 256) {
                const int s = j >> 5, cb = (j & 31) * 8;
                *(bf16x8*)(dst + s * 256 + cb) = *(const bf16x8*)(buf + s * VST_PAD + cb);
            }
        }
    }
}

// ---------------------------------------------------------------------------
// K2: grid 512 = (window, s-half). Per block: 3x {stage full slab -> buf;
//     gather on t<128 for its 32 s (text unchanged)}; ONE quantize;
//     op GEMM over nt in {0,1} -> store its 32 s columns.
//   LDS: one [64][264]bf16 = 33792 -> 2 blocks/CU (grid 512 co-resident).
// ---------------------------------------------------------------------------
__global__ __launch_bounds__(256, 2) void k_gout(
    const unsigned short* __restrict__ VBG,
    const unsigned short* __restrict__ wop, const float* __restrict__ op_b,
    const float2* __restrict__ PXY, const float* __restrict__ A,
    float* __restrict__ outp)
{
    extern __shared__ char smem[];
    unsigned short* buf = (unsigned short*)smem;   // [64][264]

    const int bid = blockIdx.x;
    const int shalf = bid >> 8;          // 0 or 1: which 32 spatial positions
    const int bw = xcd_swz(bid & 255);
    const int b  = bw >> 6;
    const int wy = (bw >> 3) & 7;
    const int wx = bw & 7;
    const int t  = threadIdx.x;
    const int lane = t & 63;
    const int g  = rfl(t >> 6);
    const int kc = (lane >> 4) * 8;
    const int sq = (shalf << 5) + (t >> 2);   // valid for t < 128
    const int dq = t & 3;

    float outA[8][8];           // f32 level-sum (t<128), persistent
    #pragma unroll
    for (int h = 0; h < 8; h++)
        #pragma unroll
        for (int j = 0; j < 8; j++) outA[h][j] = 0.f;

    for (int l = 0; l < NLV; l++) {
        // ---- stage full level slab -> buf (all 256 threads, coalesced)
        {
            const unsigned short* src = VBG + ((size_t)(bw * 3 + l)) * 64 * 256;
            for (int j = t; j < 2048; j += 256) {
                const int s = j >> 5, cb = (j & 31) * 8;
                *(bf16x8*)(buf + s * VST_PAD + cb) = *(const bf16x8*)(src + s * 256 + cb);
            }
        }
        __syncthreads();

        // ---- gather this level's 4 points for this half's 32 s (t<128)
        if (t < 128) {
            const float2* pxyp = PXY + (size_t)bw * 6144 + sq * 96;
            const float*  ap   = A   + (size_t)bw * 6144 + sq * 96;
            #pragma unroll
            for (int h = 0; h < 8; h++) {
                const int cb = h * 32 + dq * 8;
                #pragma unroll
                for (int p = 0; p < NPT; p++) {
                    const int lp = l * NPT + p;
                    float2 pxy = pxyp[h * 12 + lp];
                    float  a   = ap[h * 12 + lp];
                    float x0f = floorf(pxy.x), y0f = floorf(pxy.y);
                    float fx = pxy.x - x0f, fy = pxy.y - y0f;
                    int x0 = (int)x0f, y0 = (int)y0f;
                    int x1 = min(x0 + 1, 7), y1 = min(y0 + 1, 7);
                    float w00 = a * (1.f - fx) * (1.f - fy), w01 = a * fx * (1.f - fy);
                    float w10 = a * (1.f - fx) * fy,         w11 = a * fx * fy;
                    bf16x8 v00 = *(const bf16x8*)(buf + (y0 * 8 + x0) * VST_PAD + cb);
                    bf16x8 v01 = *(const bf16x8*)(buf + (y0 * 8 + x1) * VST_PAD + cb);
                    bf16x8 v10 = *(const bf16x8*)(buf + (y1 * 8 + x0) * VST_PAD + cb);
                    bf16x8 v11 = *(const bf16x8*)(buf + (y1 * 8 + x1) * VST_PAD + cb);
                    #pragma unroll
                    for (int j = 0; j < 8; j++)
                        outA[h][j] = fmaf(w00, bf2f(v00[j]),
                                     fmaf(w01, bf2f(v01[j]),
                                     fmaf(w10, bf2f(v10[j]),
                                     fmaf(w11, bf2f(v11[j]), outA[h][j]))));
                }
            }
        }
        __syncthreads();   // gather reads done before next level's stage
    }

    // ---- ONE bf16 quantize of the f32 level-sum -> buf rows [shalf*32,+32)
    if (t < 128) {
        #pragma unroll
        for (int h = 0; h < 8; h++)
            *(bf16x8*)(buf + sq * VST_PAD + h * 32 + dq * 8) = pack8(outA[h]);
    }
    __syncthreads();

    // ---- op GEMM (m=o, n=s over this half's 2 ntiles) + bias + store
    {
        f32x4 acc[4][2];
        #pragma unroll
        for (int mt = 0; mt < 4; mt++)
            #pragma unroll
            for (int nt = 0; nt < 2; nt++) acc[mt][nt] = (f32x4){0.f, 0.f, 0.f, 0.f};
        for (int ks = 0; ks < 8; ks++) {
            const int c = ks * 32 + kc;
            bf16x8 bq[2];
            #pragma unroll
            for (int nt = 0; nt < 2; nt++)
                bq[nt] = *(const bf16x8*)(buf + ((shalf << 5) + nt * 16 + (lane & 15)) * VST_PAD + c);
            #pragma unroll
            for (int mt = 0; mt < 4; mt++) {
                const int o = g * 64 + mt * 16 + (lane & 15);
                bf16x8 af = *(const bf16x8*)(wop + (size_t)o * CC + c);
                #pragma unroll
                for (int nt = 0; nt < 2; nt++)
                    acc[mt][nt] = __builtin_amdgcn_mfma_f32_16x16x32_bf16(
                        af, bq[nt], acc[mt][nt], 0, 0, 0);
            }
        }
        const size_t obase = (size_t)b * CC * 4096 + wy * 8 * 64 + wx * 8;
        #pragma unroll
        for (int mt = 0; mt < 4; mt++)
            #pragma unroll
            for (int nt = 0; nt < 2; nt++)
                #pragma unroll
                for (int r = 0; r < 4; r++) {
                    int o = g * 64 + mt * 16 + (lane >> 4) * 4 + r;
                    int s = (shalf << 5) + nt * 16 + (lane & 15);
                    outp[obase + (size_t)o * 4096 + (s >> 3) * 64 + (s & 7)]
                        = acc[mt][nt][r] + op_b[o];
                }
    }
}

// ---------------------------------------------------------------------------
extern "C" void kernel_launch(void* const* d_in, const int* in_sizes, int n_in,
                              void* d_out, int out_size, void* d_ws, size_t ws_size,
                              hipStream_t stream)
{
    (void)in_sizes; (void)n_in; (void)out_size; (void)ws_size;
    const float* query = (const float*)d_in[0];
    const float* values = (const float*)d_in[2];
    const float* so_w1 = (const float*)d_in[3];
    const float* so_b1 = (const float*)d_in[4];
    const float* so_g  = (const float*)d_in[5];
    const float* so_be = (const float*)d_in[6];
    const float* so_w2 = (const float*)d_in[7];
    const float* so_b2 = (const float*)d_in[8];
    const float* aw_w1 = (const float*)d_in[9];
    const float* aw_b1 = (const float*)d_in[10];
    const float* aw_g  = (const float*)d_in[11];
    const float* aw_be = (const float*)d_in[12];
    const float* aw_w2 = (const float*)d_in[13];
    const float* aw_b2 = (const float*)d_in[14];
    const float* vp_w  = (const float*)d_in[15];
    const float* vp_b  = (const float*)d_in[16];
    const float* op_w  = (const float*)d_in[17];
    const float* op_b  = (const float*)d_in[18];
    const float* lemb  = (const float*)d_in[19];

    float2* PXY = (float2*)((char*)d_ws + WS_PXY);
    float*  A   = (float*)((char*)d_ws + WS_A);
    unsigned short* WB  = (unsigned short*)((char*)d_ws + WS_WB);
    unsigned short* VBG = (unsigned short*)((char*)d_ws + WS_VBG);
    float* outp = (float*)d_out;

    WPack p = {so_w1, aw_w1, so_w2, aw_w2, vp_w, op_w, WB};
    k_cvt<<<dim3((W_TOT / 8 + 255) / 256), dim3(256), 0, stream>>>(p);

    const int lds1 = 51200;
    const int lds2 = 33792;
    hipFuncSetAttribute((const void*)k_all,  hipFuncAttributeMaxDynamicSharedMemorySize, lds1);
    hipFuncSetAttribute((const void*)k_gout, hipFuncAttributeMaxDynamicSharedMemorySize, lds2);

    k_all<<<dim3(512 + NWIN * 3), dim3(256), lds1, stream>>>(
        query, values,
        WB + W_SO1, so_b1, so_g, so_be, WB + W_SO2, so_b2,
        WB + W_AW1, aw_b1, aw_g, aw_be, WB + W_AW2, aw_b2,
        WB + W_VP, vp_b, lemb, PXY, A, VBG);
    k_gout<<<dim3(NWIN * 2), dim3(256), lds2, stream>>>(
        VBG, WB + W_OP, op_b, PXY, A, outp);
}

// Round 20
// 78.185 us; speedup vs baseline: 1.1383x; 1.1383x over previous
//
#include <hip/hip_runtime.h>

// SlidingWindowPyramidAttention — MFMA convs + register bilinear gather.
// B=4, C=256, H=W=64, ws=8 -> 256 windows x 64 positions; NH=8, HD=32, NL=3, NP=4.
//
// MFMA convention (HW-verified r3/r4): mfma(X,Y,acc) -> D[m][n];
//   X-frag: lane holds X[m = mtile+(lane&15)][k = ks*32+(lane>>4)*8 + 0..7]
//   Y-frag: lane holds Y[k same slice][n = ntile+(lane&15)]
//   D-frag: col(lane&15) = n, row = mtile + (lane>>4)*4 + r
//
// FINAL (r20): byte-exact resubmission of round 17 — the best verified
// configuration (78.37us, absmax 0.0078). The post-r17 ledger: r18 ILP
// staging = neutral (compiler re-serializes, VGPR stayed 68); r19 k_gout
// s-half split = regression (doubled staging, half-idle waves, 89us).
// Structure: k_all (grid 1280, 51.2KB LDS -> 3 blocks/CU) = heads blocks +
// vp blocks writing VBG; k_gout (grid 256, 101.4KB LDS) stages all 3 level
// slabs once, 3 gathers into f32 regs, ONE quantize, op GEMM.

#define CC   256
#define CH   128
#define NPT  4
#define NLV  3
#define SS   64
#define NWIN 256

#define QT_PAD  264   // qT row pitch (bf16)
#define HT_PAD  136   // hT row pitch (bf16)
#define AW_PAD  100   // awS row pitch (f32)
#define VST_PAD 264   // vsT row pitch (bf16)

// bf16 weight pool offsets (elements) in d_ws after PXY+A
#define W_SO1 0
#define W_AW1 32768
#define W_SO2 65536
#define W_AW2 90112
#define W_VP  102400
#define W_OP  167936
#define W_TOT 233472

// d_ws byte offsets (high-water 44.5 MB, proven envelope)
#define WS_PXY  0
#define WS_A    12582912
#define WS_WB   18874368
#define WS_VBG  19341312   // bf16 [256*3][64][256] = 25165824 B

typedef short bf16x8 __attribute__((ext_vector_type(8)));
typedef short bf16x4 __attribute__((ext_vector_type(4)));
typedef float f32x4  __attribute__((ext_vector_type(4)));

__device__ __forceinline__ int rfl(int x) { return __builtin_amdgcn_readfirstlane(x); }

__device__ __forceinline__ unsigned short f2bf(float f) {
    unsigned u = __builtin_bit_cast(unsigned, f);
    u += 0x7FFFu + ((u >> 16) & 1u);           // RNE
    return (unsigned short)(u >> 16);
}
__device__ __forceinline__ float bf2f(short s) {
    unsigned u = ((unsigned)(unsigned short)s) << 16;
    return __builtin_bit_cast(float, u);
}
__device__ __forceinline__ bf16x8 pack8(const float* v) {
    bf16x8 r;
    #pragma unroll
    for (int i = 0; i < 8; i++) r[i] = (short)f2bf(v[i]);
    return r;
}
__device__ __forceinline__ int xcd_swz(int bid) {   // 256 blocks, bijective
    return ((bid & 7) << 5) | (bid >> 3);
}

// ---------------------------------------------------------------------------
// K0: fp32 -> bf16 weight conversion (idempotent).
// ---------------------------------------------------------------------------
struct WPack {
    const float *s0, *s1, *s2, *s3, *s4, *s5;
    unsigned short* d;
};
__global__ __launch_bounds__(256) void k_cvt(WPack p) {
    int i = (blockIdx.x * 256 + threadIdx.x) * 8;
    if (i >= W_TOT) return;
    const float* src; int off;
    if      (i < W_AW1) { src = p.s0; off = W_SO1; }
    else if (i < W_SO2) { src = p.s1; off = W_AW1; }
    else if (i < W_AW2) { src = p.s2; off = W_SO2; }
    else if (i < W_VP)  { src = p.s3; off = W_AW2; }
    else if (i < W_OP)  { src = p.s4; off = W_VP;  }
    else                { src = p.s5; off = W_OP;  }
    const float* s = src + (i - off);
    float4 a = *(const float4*)s;
    float4 b = *(const float4*)(s + 4);
    float tmp[8] = {a.x, a.y, a.z, a.w, b.x, b.y, b.z, b.w};
    *(bf16x8*)(p.d + i) = pack8(tmp);
}

// ---------------------------------------------------------------------------
// K1: merged heads + vp-projection, 51200 B LDS -> 3 blocks/CU.
//   bid <  512: heads (kind = bid>>8), aliased-awS layout verbatim.
//   bid >= 512: vp per (window, level), single-buffer form verbatim,
//               then coalesced bit-exact copy buf -> VBG global.
// ---------------------------------------------------------------------------
__global__ __launch_bounds__(256, 2) void k_all(
    const float* __restrict__ query, const float* __restrict__ values,
    const unsigned short* __restrict__ wso1, const float* __restrict__ so_b1,
    const float* __restrict__ so_g,  const float* __restrict__ so_be,
    const unsigned short* __restrict__ wso2, const float* __restrict__ so_b2,
    const unsigned short* __restrict__ waw1, const float* __restrict__ aw_b1,
    const float* __restrict__ aw_g,  const float* __restrict__ aw_be,
    const unsigned short* __restrict__ waw2, const float* __restrict__ aw_b2,
    const unsigned short* __restrict__ wvp, const float* __restrict__ vp_b,
    const float* __restrict__ lemb,
    float2* __restrict__ PXY, float* __restrict__ A,
    unsigned short* __restrict__ VBG)
{
    extern __shared__ char smem[];
    const int bid = blockIdx.x;
    const int t  = threadIdx.x;
    const int lane = t & 63;
    const int g  = rfl(t >> 6);
    const int kc = (lane >> 4) * 8;
    const int srow = (lane >> 3) * 64 + (lane & 7);

    if (bid < 512) {
        // ======= heads path (aliased-awS layout) ============================
        unsigned short* qT = (unsigned short*)smem;                 // [64][264]
        unsigned short* hT = (unsigned short*)(smem + 33792);       // [64][136]
        float* awS = (float*)smem;                                  // aliases qT

        const int kind = bid >> 8;
        const int bw = xcd_swz(bid & 255);
        const int b  = bw >> 6;
        const int wy = (bw >> 3) & 7;
        const int wx = bw & 7;

        const unsigned short* w1 = kind ? waw1 : wso1;
        const float* B1 = kind ? aw_b1 : so_b1;
        const float* G  = kind ? aw_g  : so_g;
        const float* Be = kind ? aw_be : so_be;

        // ---- stage qT[s][c] bf16
        {
            const float* qb = query + (size_t)b * CC * 4096 + wy * 8 * 64 + wx * 8;
            for (int it = 0; it < 8; it++) {
                int cg = g * 8 + it;
                float tmp[8];
                #pragma unroll
                for (int j = 0; j < 8; j++)
                    tmp[j] = qb[(size_t)(cg * 8 + j) * 4096 + srow];
                *(bf16x8*)(qT + lane * QT_PAD + cg * 8) = pack8(tmp);
            }
        }
        __syncthreads();

        // ---- conv1 GEMM (256->128), wave g -> rows [g*32,+32)
        f32x4 acc1[2][4];
        #pragma unroll
        for (int mt = 0; mt < 2; mt++)
            #pragma unroll
            for (int nt = 0; nt < 4; nt++) acc1[mt][nt] = (f32x4){0.f, 0.f, 0.f, 0.f};
        for (int ks = 0; ks < 8; ks++) {
            const int c = ks * 32 + kc;
            bf16x8 bq[4];
            #pragma unroll
            for (int nt = 0; nt < 4; nt++)
                bq[nt] = *(const bf16x8*)(qT + (nt * 16 + (lane & 15)) * QT_PAD + c);
            #pragma unroll
            for (int mt = 0; mt < 2; mt++) {
                const int o = g * 32 + mt * 16 + (lane & 15);
                bf16x8 af = *(const bf16x8*)(w1 + (size_t)o * CC + c);
                #pragma unroll
                for (int nt = 0; nt < 4; nt++)
                    acc1[mt][nt] = __builtin_amdgcn_mfma_f32_16x16x32_bf16(af, bq[nt], acc1[mt][nt], 0, 0, 0);
            }
        }

        // ---- GN(+bias,ReLU): wave g's mtile mt == GN group 2g+mt
        #pragma unroll
        for (int mt = 0; mt < 2; mt++) {
            const int c2b = g * 32 + mt * 16 + ((lane >> 4) << 2);
            float4 bv = *(const float4*)(B1 + c2b);
            float s = 0.f, q = 0.f;
            #pragma unroll
            for (int nt = 0; nt < 4; nt++)
                #pragma unroll
                for (int r = 0; r < 4; r++) {
                    float v = acc1[mt][nt][r] + ((const float*)&bv)[r];
                    acc1[mt][nt][r] = v;
                    s += v; q += v * v;
                }
            #pragma unroll
            for (int off = 1; off < 64; off <<= 1) {
                s += __shfl_xor(s, off, 64);
                q += __shfl_xor(q, off, 64);
            }
            const float mu = s * (1.f / 1024.f);
            const float rs = rsqrtf(q * (1.f / 1024.f) - mu * mu + 1e-5f);
            float4 Gv  = *(const float4*)(G + c2b);
            float4 Bev = *(const float4*)(Be + c2b);
            #pragma unroll
            for (int nt = 0; nt < 4; nt++) {
                int ss = nt * 16 + (lane & 15);
                bf16x4 pk;
                #pragma unroll
                for (int r = 0; r < 4; r++) {
                    float val = (acc1[mt][nt][r] - mu) * rs * ((const float*)&Gv)[r]
                                + ((const float*)&Bev)[r];
                    pk[r] = (short)f2bf(fmaxf(val, 0.f));
                }
                *(bf16x4*)(hT + ss * HT_PAD + c2b) = pk;
            }
        }
        __syncthreads();   // qT reads done; awS may now overwrite its space

        if (!kind) {
            // ---- conv2-so (128->192) -> PXY
            f32x4 acc2[3][4];
            #pragma unroll
            for (int mt = 0; mt < 3; mt++)
                #pragma unroll
                for (int nt = 0; nt < 4; nt++) acc2[mt][nt] = (f32x4){0.f, 0.f, 0.f, 0.f};
            for (int ks = 0; ks < 4; ks++) {
                const int c = ks * 32 + kc;
                bf16x8 bh[4];
                #pragma unroll
                for (int nt = 0; nt < 4; nt++)
                    bh[nt] = *(const bf16x8*)(hT + (nt * 16 + (lane & 15)) * HT_PAD + c);
                #pragma unroll
                for (int mt = 0; mt < 3; mt++) {
                    const int o = g * 48 + mt * 16 + (lane & 15);
                    bf16x8 af = *(const bf16x8*)(wso2 + (size_t)o * CH + c);
                    #pragma unroll
                    for (int nt = 0; nt < 4; nt++)
                        acc2[mt][nt] = __builtin_amdgcn_mfma_f32_16x16x32_bf16(af, bh[nt], acc2[mt][nt], 0, 0, 0);
                }
            }
            #pragma unroll
            for (int mt = 0; mt < 3; mt++) {
                const int o_base = g * 48 + mt * 16 + ((lane >> 4) << 2);
                float4 sb = *(const float4*)(so_b2 + o_base);
                #pragma unroll
                for (int nt = 0; nt < 4; nt++) {
                    const int s = nt * 16 + (lane & 15);
                    const float refx = (s & 7) * (1.f / 7.f);
                    const float refy = (s >> 3) * (1.f / 7.f);
                    auto mkp = [](float refc, float oc) {
                        float lc = fminf(fmaxf(refc + oc * 0.125f, 0.f), 1.f);
                        return fminf(fmaxf(lc * 8.f - 0.5f, 0.f), 7.f);
                    };
                    float4 out4;
                    out4.x = mkp(refx, acc2[mt][nt][0] + sb.x);
                    out4.y = mkp(refy, acc2[mt][nt][1] + sb.y);
                    out4.z = mkp(refx, acc2[mt][nt][2] + sb.z);
                    out4.w = mkp(refy, acc2[mt][nt][3] + sb.w);
                    *(float4*)(PXY + (size_t)bw * 6144 + s * 96 + (o_base >> 1)) = out4;
                }
            }
        } else {
            // ---- conv2-aw (128->96) -> awS logits
            for (int mm = 0; mm < 2; mm++) {
                const int mtile = g + mm * 4;
                if (mtile >= 6) break;   // wave-uniform
                f32x4 acc3[4];
                #pragma unroll
                for (int nt = 0; nt < 4; nt++) acc3[nt] = (f32x4){0.f, 0.f, 0.f, 0.f};
                for (int ks = 0; ks < 4; ks++) {
                    const int c = ks * 32 + kc;
                    const int o = mtile * 16 + (lane & 15);
                    bf16x8 af = *(const bf16x8*)(waw2 + (size_t)o * CH + c);
                    #pragma unroll
                    for (int nt = 0; nt < 4; nt++) {
                        bf16x8 bh = *(const bf16x8*)(hT + (nt * 16 + (lane & 15)) * HT_PAD + c);
                        acc3[nt] = __builtin_amdgcn_mfma_f32_16x16x32_bf16(af, bh, acc3[nt], 0, 0, 0);
                    }
                }
                const int o_base = mtile * 16 + ((lane >> 4) << 2);
                float4 ab = *(const float4*)(aw_b2 + o_base);
                #pragma unroll
                for (int nt = 0; nt < 4; nt++) {
                    const int s = nt * 16 + (lane & 15);
                    float4 o4;
                    o4.x = acc3[nt][0] + ab.x;
                    o4.y = acc3[nt][1] + ab.y;
                    o4.z = acc3[nt][2] + ab.z;
                    o4.w = acc3[nt][3] + ab.w;
                    *(float4*)(awS + s * AW_PAD + o_base) = o4;
                }
            }
            __syncthreads();
            // softmax over 12 per (s,h)
            for (int task = t; task < 512; task += 256) {
                const int s = task >> 3, h = task & 7;
                const float* row = awS + s * AW_PAD + h * 12;
                float4 r0 = *(const float4*)row;
                float4 r1 = *(const float4*)(row + 4);
                float4 r2 = *(const float4*)(row + 8);
                float v[12] = {r0.x, r0.y, r0.z, r0.w, r1.x, r1.y, r1.z, r1.w,
                               r2.x, r2.y, r2.z, r2.w};
                float m = v[0];
                #pragma unroll
                for (int j = 1; j < 12; j++) m = fmaxf(m, v[j]);
                float sum = 0.f;
                #pragma unroll
                for (int j = 0; j < 12; j++) { v[j] = __expf(v[j] - m); sum += v[j]; }
                float rinv = 1.f / sum;
                float* dst = A + (size_t)bw * 6144 + s * 96 + h * 12;
                float4 w0 = {v[0] * rinv, v[1] * rinv, v[2] * rinv, v[3] * rinv};
                float4 w1v = {v[4] * rinv, v[5] * rinv, v[6] * rinv, v[7] * rinv};
                float4 w2 = {v[8] * rinv, v[9] * rinv, v[10] * rinv, v[11] * rinv};
                *(float4*)dst = w0;
                *(float4*)(dst + 4) = w1v;
                *(float4*)(dst + 8) = w2;
            }
        }
    } else {
        // ======= vp path (single-buffer form) ===============================
        unsigned short* buf = (unsigned short*)smem;   // [64][264]: stage, then Vb

        const int id = bid - 512;
        const int l  = id >> 8;
        const int bw = xcd_swz(id & 255);
        const int b  = bw >> 6;
        const int wy = (bw >> 3) & 7;
        const int wx = bw & 7;

        // ---- stage buf[s][c] bf16 (+ level embed)
        {
            const float* vb = values + ((size_t)(b * NLV + l) * CC) * 4096 + wy * 8 * 64 + wx * 8;
            const float* le = lemb + l * CC;
            for (int it = 0; it < 8; it++) {
                int cg = g * 8 + it;
                float tmp[8];
                #pragma unroll
                for (int j = 0; j < 8; j++) {
                    int c = cg * 8 + j;
                    tmp[j] = vb[(size_t)c * 4096 + srow] + le[c];
                }
                *(bf16x8*)(buf + lane * VST_PAD + cg * 8) = pack8(tmp);
            }
        }
        __syncthreads();

        // ---- vp GEMM (m=o, n=s): wave g -> o in [g*64,+64)
        {
            f32x4 acc[4][4];
            #pragma unroll
            for (int mt = 0; mt < 4; mt++)
                #pragma unroll
                for (int nt = 0; nt < 4; nt++) acc[mt][nt] = (f32x4){0.f, 0.f, 0.f, 0.f};
            for (int ks = 0; ks < 8; ks++) {
                const int c = ks * 32 + kc;
                bf16x8 bf[4];
                #pragma unroll
                for (int nt = 0; nt < 4; nt++)
                    bf[nt] = *(const bf16x8*)(buf + (nt * 16 + (lane & 15)) * VST_PAD + c);
                #pragma unroll
                for (int mt = 0; mt < 4; mt++) {
                    const int o = g * 64 + mt * 16 + (lane & 15);
                    bf16x8 af = *(const bf16x8*)(wvp + (size_t)o * CC + c);
                    #pragma unroll
                    for (int nt = 0; nt < 4; nt++)
                        acc[mt][nt] = __builtin_amdgcn_mfma_f32_16x16x32_bf16(
                            af, bf[nt], acc[mt][nt], 0, 0, 0);
                }
            }
            __syncthreads();   // all stage reads done; buf may be overwritten

            // ---- write Vb[s][o] bf16 into the same buffer
            #pragma unroll
            for (int mt = 0; mt < 4; mt++) {
                const int o0 = g * 64 + mt * 16 + ((lane >> 4) << 2);
                float4 bv = *(const float4*)(vp_b + o0);
                #pragma unroll
                for (int nt = 0; nt < 4; nt++) {
                    const int s = nt * 16 + (lane & 15);
                    bf16x4 pk;
                    #pragma unroll
                    for (int r = 0; r < 4; r++)
                        pk[r] = (short)f2bf(acc[mt][nt][r] + ((const float*)&bv)[r]);
                    *(bf16x4*)(buf + s * VST_PAD + o0) = pk;
                }
            }
        }
        __syncthreads();

        // ---- bit-exact coalesced copy buf LDS -> VBG global (128 B/thread)
        {
            unsigned short* dst = VBG + ((size_t)(bw * 3 + l)) * 64 * 256;
            for (int j = t; j < 2048; j += 256) {
                const int s = j >> 5, cb = (j & 31) * 8;
                *(bf16x8*)(dst + s * 256 + cb) = *(const bf16x8*)(buf + s * VST_PAD + cb);
            }
        }
    }
}

// ---------------------------------------------------------------------------
// K2: per window: stage ALL 3 VBG level slabs -> 3 LDS bufs (one barrier),
//     then 3x gather (verbatim text); ONE quantize; op GEMM -> store.
//   LDS: 3 x [64][264]bf16 = 101376 B (grid=256 -> 1 block/CU, LDS is free).
// ---------------------------------------------------------------------------
__global__ __launch_bounds__(256, 1) void k_gout(
    const unsigned short* __restrict__ VBG,
    const unsigned short* __restrict__ wop, const float* __restrict__ op_b,
    const float2* __restrict__ PXY, const float* __restrict__ A,
    float* __restrict__ outp)
{
    extern __shared__ char smem[];

    const int bw = xcd_swz(blockIdx.x);
    const int b  = bw >> 6;
    const int wy = (bw >> 3) & 7;
    const int wx = bw & 7;
    const int t  = threadIdx.x;
    const int lane = t & 63;
    const int g  = rfl(t >> 6);
    const int kc = (lane >> 4) * 8;
    const int sq = t >> 2;      // gather: spatial position
    const int dq = t & 3;       // gather: 8-channel slice within head

    // ---- stage ALL 3 level slabs (back-to-back loads, single barrier)
    #pragma unroll
    for (int l = 0; l < NLV; l++) {
        unsigned short* bufl = (unsigned short*)(smem + l * 33792);
        const unsigned short* src = VBG + ((size_t)(bw * 3 + l)) * 64 * 256;
        for (int j = t; j < 2048; j += 256) {
            const int s = j >> 5, cb = (j & 31) * 8;
            *(bf16x8*)(bufl + s * VST_PAD + cb) = *(const bf16x8*)(src + s * 256 + cb);
        }
    }
    __syncthreads();

    float outA[8][8];           // f32 level-sum, persistent across levels
    #pragma unroll
    for (int h = 0; h < 8; h++)
        #pragma unroll
        for (int j = 0; j < 8; j++) outA[h][j] = 0.f;

    for (int l = 0; l < NLV; l++) {
        unsigned short* buf = (unsigned short*)(smem + l * 33792);
        // ---- gather this level's 4 points; accumulate f32 into outA
        {
            const float2* pxyp = PXY + (size_t)bw * 6144 + sq * 96;
            const float*  ap   = A   + (size_t)bw * 6144 + sq * 96;
            #pragma unroll
            for (int h = 0; h < 8; h++) {
                const int cb = h * 32 + dq * 8;
                #pragma unroll
                for (int p = 0; p < NPT; p++) {
                    const int lp = l * NPT + p;
                    float2 pxy = pxyp[h * 12 + lp];
                    float  a   = ap[h * 12 + lp];
                    float x0f = floorf(pxy.x), y0f = floorf(pxy.y);
                    float fx = pxy.x - x0f, fy = pxy.y - y0f;
                    int x0 = (int)x0f, y0 = (int)y0f;
                    int x1 = min(x0 + 1, 7), y1 = min(y0 + 1, 7);
                    float w00 = a * (1.f - fx) * (1.f - fy), w01 = a * fx * (1.f - fy);
                    float w10 = a * (1.f - fx) * fy,         w11 = a * fx * fy;
                    bf16x8 v00 = *(const bf16x8*)(buf + (y0 * 8 + x0) * VST_PAD + cb);
                    bf16x8 v01 = *(const bf16x8*)(buf + (y0 * 8 + x1) * VST_PAD + cb);
                    bf16x8 v10 = *(const bf16x8*)(buf + (y1 * 8 + x0) * VST_PAD + cb);
                    bf16x8 v11 = *(const bf16x8*)(buf + (y1 * 8 + x1) * VST_PAD + cb);
                    #pragma unroll
                    for (int j = 0; j < 8; j++)
                        outA[h][j] = fmaf(w00, bf2f(v00[j]),
                                     fmaf(w01, bf2f(v01[j]),
                                     fmaf(w10, bf2f(v10[j]),
                                     fmaf(w11, bf2f(v11[j]), outA[h][j]))));
                }
            }
        }
    }
    __syncthreads();   // all gather reads done before quantize overwrites buf0

    // ---- ONE bf16 quantize of the f32 level-sum -> buf0[s][c]
    {
        unsigned short* buf = (unsigned short*)smem;
        #pragma unroll
        for (int h = 0; h < 8; h++)
            *(bf16x8*)(buf + sq * VST_PAD + h * 32 + dq * 8) = pack8(outA[h]);
    }
    __syncthreads();

    // ---- op GEMM (m=o, n=s) + bias + window-reverse store
    {
        unsigned short* buf = (unsigned short*)smem;
        f32x4 acc[4][4];
        #pragma unroll
        for (int mt = 0; mt < 4; mt++)
            #pragma unroll
            for (int nt = 0; nt < 4; nt++) acc[mt][nt] = (f32x4){0.f, 0.f, 0.f, 0.f};
        for (int ks = 0; ks < 8; ks++) {
            const int c = ks * 32 + kc;
            bf16x8 bq[4];
            #pragma unroll
            for (int nt = 0; nt < 4; nt++)
                bq[nt] = *(const bf16x8*)(buf + (nt * 16 + (lane & 15)) * VST_PAD + c);
            #pragma unroll
            for (int mt = 0; mt < 4; mt++) {
                const int o = g * 64 + mt * 16 + (lane & 15);
                bf16x8 af = *(const bf16x8*)(wop + (size_t)o * CC + c);
                #pragma unroll
                for (int nt = 0; nt < 4; nt++)
                    acc[mt][nt] = __builtin_amdgcn_mfma_f32_16x16x32_bf16(
                        af, bq[nt], acc[mt][nt], 0, 0, 0);
            }
        }
        const size_t obase = (size_t)b * CC * 4096 + wy * 8 * 64 + wx * 8;
        #pragma unroll
        for (int mt = 0; mt < 4; mt++)
            #pragma unroll
            for (int nt = 0; nt < 4; nt++)
                #pragma unroll
                for (int r = 0; r < 4; r++) {
                    int o = g * 64 + mt * 16 + (lane >> 4) * 4 + r;
                    int s = nt * 16 + (lane & 15);
                    outp[obase + (size_t)o * 4096 + (s >> 3) * 64 + (s & 7)]
                        = acc[mt][nt][r] + op_b[o];
                }
    }
}

// ---------------------------------------------------------------------------
extern "C" void kernel_launch(void* const* d_in, const int* in_sizes, int n_in,
                              void* d_out, int out_size, void* d_ws, size_t ws_size,
                              hipStream_t stream)
{
    (void)in_sizes; (void)n_in; (void)out_size; (void)ws_size;
    const float* query = (const float*)d_in[0];
    const float* values = (const float*)d_in[2];
    const float* so_w1 = (const float*)d_in[3];
    const float* so_b1 = (const float*)d_in[4];
    const float* so_g  = (const float*)d_in[5];
    const float* so_be = (const float*)d_in[6];
    const float* so_w2 = (const float*)d_in[7];
    const float* so_b2 = (const float*)d_in[8];
    const float* aw_w1 = (const float*)d_in[9];
    const float* aw_b1 = (const float*)d_in[10];
    const float* aw_g  = (const float*)d_in[11];
    const float* aw_be = (const float*)d_in[12];
    const float* aw_w2 = (const float*)d_in[13];
    const float* aw_b2 = (const float*)d_in[14];
    const float* vp_w  = (const float*)d_in[15];
    const float* vp_b  = (const float*)d_in[16];
    const float* op_w  = (const float*)d_in[17];
    const float* op_b  = (const float*)d_in[18];
    const float* lemb  = (const float*)d_in[19];

    float2* PXY = (float2*)((char*)d_ws + WS_PXY);
    float*  A   = (float*)((char*)d_ws + WS_A);
    unsigned short* WB  = (unsigned short*)((char*)d_ws + WS_WB);
    unsigned short* VBG = (unsigned short*)((char*)d_ws + WS_VBG);
    float* outp = (float*)d_out;

    WPack p = {so_w1, aw_w1, so_w2, aw_w2, vp_w, op_w, WB};
    k_cvt<<<dim3((W_TOT / 8 + 255) / 256), dim3(256), 0, stream>>>(p);

    const int lds1 = 51200;
    const int lds2 = 3 * 33792;   // 101376
    hipFuncSetAttribute((const void*)k_all,  hipFuncAttributeMaxDynamicSharedMemorySize, lds1);
    hipFuncSetAttribute((const void*)k_gout, hipFuncAttributeMaxDynamicSharedMemorySize, lds2);

    k_all<<<dim3(512 + NWIN * 3), dim3(256), lds1, stream>>>(
        query, values,
        WB + W_SO1, so_b1, so_g, so_be, WB + W_SO2, so_b2,
        WB + W_AW1, aw_b1, aw_g, aw_be, WB + W_AW2, aw_b2,
        WB + W_VP, vp_b, lemb, PXY, A, VBG);
    k_gout<<<dim3(NWIN), dim3(256), lds2, stream>>>(
        VBG, WB + W_OP, op_b, PXY, A, outp);
}